// Round 13
// baseline (3079.664 us; speedup 1.0000x reference)
//
#include <hip/hip_runtime.h>
#include <hip/hip_bf16.h>
#include <stdint.h>

// Sizes (fixed by the problem)
#define BB 512      // batch
#define TT 128      // seq len
#define DD 1024     // input dim / hidden
#define HH 1024
#define G3 3072     // 3*H

typedef __bf16 bft;
typedef __bf16 bf16x8 __attribute__((ext_vector_type(8)));
typedef float f32x4 __attribute__((ext_vector_type(4)));

// async global->LDS, 16B per lane. lds base must be wave-uniform; lane i's data
// lands at base + i*16, so lane i's global ptr must be the data for that slot.
__device__ __forceinline__ void gl_lds16(const bft* g, void* lds_base_uniform) {
  __builtin_amdgcn_global_load_lds(
      (const __attribute__((address_space(1))) void*)g,
      (__attribute__((address_space(3))) void*)lds_base_uniform,
      16, 0, 0);
}

// ---- write-through (sc0 sc1) stores: retire at coherence point ----
__device__ __forceinline__ void st_wt_bf16(bft* p, float v) {
  bft h = (bft)v;
  union { bft h; unsigned short u; } cv; cv.h = h;
  unsigned int uv = cv.u;
  asm volatile("global_store_short %0, %1, off sc0 sc1" :: "v"(p), "v"(uv) : "memory");
}
__device__ __forceinline__ void st_wt_u32(int* p, int v) {
  asm volatile("global_store_dword %0, %1, off sc0 sc1" :: "v"(p), "v"(v) : "memory");
}
// coherent load (bypass L1/L2 -> always fresh)
__device__ __forceinline__ int ld_co_u32(const int* p) {
  int v;
  asm volatile("global_load_dword %0, %1, off sc0 sc1\n\ts_waitcnt vmcnt(0)"
               : "=v"(v) : "v"(p) : "memory");
  return v;
}

// ---- fast transcendentals (v_exp_f32 = 2^x, v_rcp_f32), ~1ulp ----
__device__ __forceinline__ float fexp2(float x) {
  float r; asm("v_exp_f32 %0, %1" : "=v"(r) : "v"(x)); return r;
}
__device__ __forceinline__ float frcp(float x) {
  float r; asm("v_rcp_f32 %0, %1" : "=v"(r) : "v"(x)); return r;
}
#define LOG2E 1.44269504f

// ---------------- fp32 -> bf16 convert (weights) ----------------
__global__ void k_cvt(const float* __restrict__ in, bft* __restrict__ out, long n) {
  long i = ((long)blockIdx.x * blockDim.x + threadIdx.x) * 8;
  long stride = (long)gridDim.x * blockDim.x * 8;
  for (; i < n; i += stride) {
    float4 a = *(const float4*)(in + i);
    float4 b = *(const float4*)(in + i + 4);
    bf16x8 r;
    r[0] = (bft)a.x; r[1] = (bft)a.y; r[2] = (bft)a.z; r[3] = (bft)a.w;
    r[4] = (bft)b.x; r[5] = (bft)b.y; r[6] = (bft)b.z; r[7] = (bft)b.w;
    *(bf16x8*)(out + i) = r;
  }
}

// ---------------- generic bf16 GEMM: C[m,n] = sum_k A[m,k]*W[n,k] + bias[n] --
// BM=BN=128, BK=64, 256 threads (4 waves 2x2, each wave 64x64 = 4x4 frags).
// AMODE 0: A bf16 packed, row m at A + m*lda.
// AMODE 1: A fp32 (x, [b][t][d] => row m = b*TT+t is identity); staging does
//          fp32 load -> bf16 cvt -> swizzled ds_write (fused gather+convert).
// AMODE 2: A bf16 t-major hseq [t][b][d]: row m=b*TT+t -> grow = t*BB + b.
// EPI 0: bf16 store C[row*ldc+col]. EPI 1: fp32 silu store.
// EPI 2: bf16 store to xp layout [t][g][b][j]: row=(b,t), col=(g,j) ->
//        idx = ((t*3+g)*BB + b)*1024 + j  (per-step-contiguous for k_persist).
// SWZ 1 (requires grid (24,512)): XCD-aware 2-level swizzle: 8 XCDs as 4(m)x2(n)
// slabs of 128m x 12n tiles; within slab 4m x 4n L2 blocks, W-block-inner.
template<int AMODE, int EPI, int SWZ>
__launch_bounds__(256)
__global__ void k_gemm(const void* __restrict__ Ap, long lda,
                       const bft* __restrict__ W, long ldw,
                       const float* __restrict__ bias,
                       void* __restrict__ Cout, long ldc,
                       int K) {
  __shared__ unsigned char sm[32768];   // A tile 16KB | W tile 16KB
  const int tid  = threadIdx.x;
  const int lane = tid & 63;
  const int wid  = tid >> 6;
  int m_t, n_t;
  if (SWZ) {
    int lin = blockIdx.x + blockIdx.y * gridDim.x;   // [0, 12288)
    int xcd = lin & 7, idx = lin >> 3;               // idx in [0, 1536)
    int xm = xcd >> 1, xn = xcd & 1;
    int bi = idx >> 4, wi = idx & 15;                // bi in [0,96)
    int nb = bi / 32, mb = bi - nb * 32;             // nb<3, mb<32
    m_t = xm * 128 + mb * 4 + (wi & 3);              // [0,512)
    n_t = xn * 12 + nb * 4 + (wi >> 2);              // [0,24)
  } else { m_t = blockIdx.y; n_t = blockIdx.x; }
  const int m0 = m_t * 128;
  const int n0 = n_t * 128;
  const int wm = wid >> 1, wn = wid & 1;

  f32x4 acc[4][4] = {};

  for (int k0 = 0; k0 < K; k0 += 64) {
    if (AMODE == 1) {
      const float* Af = (const float*)Ap;
#pragma unroll
      for (int s = 0; s < 4; ++s) {
        int seg = wid * 4 + s;
        int row = seg * 8 + (lane >> 3);
        long grow = (long)(m0 + row);
        const float* src = Af + grow * lda + k0 + (lane & 7) * 8;
        float4 a  = *(const float4*)src;
        float4 b2 = *(const float4*)(src + 4);
        bf16x8 r;
        r[0] = (bft)a.x;  r[1] = (bft)a.y;  r[2] = (bft)a.z;  r[3] = (bft)a.w;
        r[4] = (bft)b2.x; r[5] = (bft)b2.y; r[6] = (bft)b2.z; r[7] = (bft)b2.w;
        *(bf16x8*)(sm + seg * 1024 + (lane >> 3) * 128 +
                   (((lane & 7) * 16) ^ ((row & 7) << 4))) = r;
      }
    } else {
      const bft* Ab = (const bft*)Ap;
#pragma unroll
      for (int s = 0; s < 4; ++s) {
        int seg = wid * 4 + s;
        int row = seg * 8 + (lane >> 3);
        int cbs = ((lane & 7) * 16) ^ ((row & 7) << 4);
        int mr = m0 + row;
        long grow;
        if (AMODE == 0) grow = mr;
        else            grow = (long)(mr & (TT - 1)) * BB + (mr >> 7);
        gl_lds16(Ab + grow * lda + k0 + (cbs >> 1), sm + seg * 1024);
      }
    }
#pragma unroll
    for (int s = 0; s < 4; ++s) {
      int seg = wid * 4 + s;
      int row = seg * 8 + (lane >> 3);
      int cbs = ((lane & 7) * 16) ^ ((row & 7) << 4);
      gl_lds16(W + (long)(n0 + row) * ldw + k0 + (cbs >> 1), sm + 16384 + seg * 1024);
    }
    __syncthreads();
#pragma unroll
    for (int ks = 0; ks < 2; ++ks) {
      int kb = ks * 64 + (lane >> 4) * 16;
      bf16x8 aF[4], bF[4];
#pragma unroll
      for (int mi = 0; mi < 4; ++mi) {
        int row = wm * 64 + mi * 16 + (lane & 15);
        aF[mi] = *(const bf16x8*)(sm + row * 128 + (kb ^ ((row & 7) << 4)));
      }
#pragma unroll
      for (int ni = 0; ni < 4; ++ni) {
        int row = wn * 64 + ni * 16 + (lane & 15);
        bF[ni] = *(const bf16x8*)(sm + 16384 + row * 128 + (kb ^ ((row & 7) << 4)));
      }
#pragma unroll
      for (int mi = 0; mi < 4; ++mi)
#pragma unroll
        for (int ni = 0; ni < 4; ++ni)
          acc[mi][ni] = __builtin_amdgcn_mfma_f32_16x16x32_bf16(aF[mi], bF[ni], acc[mi][ni], 0, 0, 0);
    }
    __syncthreads();
  }

#pragma unroll
  for (int mi = 0; mi < 4; ++mi)
#pragma unroll
    for (int ni = 0; ni < 4; ++ni) {
      int col = n0 + wn * 64 + ni * 16 + (lane & 15);
      float bv = bias[col];
#pragma unroll
      for (int r = 0; r < 4; ++r) {
        long row = m0 + wm * 64 + mi * 16 + (lane >> 4) * 4 + r;
        float v = acc[mi][ni][r] + bv;
        if (EPI == 0) {
          ((bft*)Cout)[row * ldc + col] = (bft)v;
        } else if (EPI == 1) {
          ((float*)Cout)[row * ldc + col] = v / (1.f + expf(-v));
        } else {
          int t = (int)(row & (TT - 1));
          long b = row >> 7;
          int g = col >> 10, jj = col & 1023;
          ((bft*)Cout)[(((long)t * 3 + g) * BB + b) * 1024 + jj] = (bft)v;
        }
      }
    }
}

// ---------------- persistent GRU full-sequence kernel (one per layer) -------
// 256 WGs = 4 m-groups (XCD pairs) x 64 j-tiles, 1 WG/CU (4 waves, 1/SIMD).
// W_hh r,z gates pinned in AGPRs (256/wave); n gate (16x1024, 32KB swizzled)
// in LDS. Runs ALL TT=128 steps in one dispatch. A (h_prev 128x1024 bf16)
// staged via 4-deep LDS pipeline, counted per-wave vmcnt (each wave stages and
// reads only its own 32 rows -> no cross-wave LDS hazard, no k-loop barriers).
// xp is [t][g][b][j] (r13): per-step xg reads stream one contiguous 3MB block
// instead of 768KB-strided 2B scatter -> the k=0 vmcnt drain of the (older)
// xg loads is fast. h fp32 register-carried; written per step to hseq[t]
// (unique slot, t-major) via write-through stores; per-WG flag after;
// consumers poll their m-group's 64 flags. No cache fences.
__launch_bounds__(256, 1)
__global__ void k_persist(const bft* __restrict__ whh, const float* __restrict__ bhh,
                          const bft* __restrict__ xp,
                          bft* __restrict__ hseq,     // [TT][BB][DD] in/out
                          int* __restrict__ flags, int pbase) {
  __shared__ unsigned char sm[98304];           // W_n 32KB | A 4x16KB
  unsigned char* smW = sm;
  unsigned char* smA = sm + 32768;

  const int tid  = threadIdx.x;
  const int lane = tid & 63;
  const int wid  = tid >> 6;
  const int bid  = blockIdx.x;
  const int xcd = bid & 7, loc = bid >> 3;
  const int mt = xcd >> 1;                // m-group = XCD pair
  const int nt = (xcd & 1) * 32 + loc;    // 0..63 j-tile within group
  const int j0 = nt * 16;
  const int m0 = mt * 128;
  const int j  = j0 + (lane & 15);
  int* gflags = flags + mt * 64;

  // ---- n-gate W slice into LDS (16 rows x 2048B, XOR-swizzled source)
#pragma unroll
  for (int s8 = 0; s8 < 8; ++s8) {
    int s = wid * 8 + s8;
    int row = s >> 1;
    int half = s & 1;
    int hb = half * 1024 + lane * 16;
    int sb = hb ^ ((row & 7) << 4);
    long grow = (long)(2 * 1024 + j0 + row);
    gl_lds16(whh + grow * 1024 + (sb >> 1), smW + s * 1024);
  }

  // ---- r,z gate W slice into AGPRs: 64 bf16x8 frags, pinned via "a" class
  bf16x8 wrz[2][16][2];
#pragma unroll
  for (int g = 0; g < 2; ++g) {
    const bft* wbase = whh + (((long)g * 1024 + j) << 10) + ((lane >> 4) * 8);
#pragma unroll
    for (int k = 0; k < 16; ++k)
#pragma unroll
      for (int ks = 0; ks < 2; ++ks) {
        bf16x8 wl = *(const bf16x8*)(wbase + k * 64 + ks * 32);
        asm("" : "=a"(wrz[g][k][ks]) : "0"(wl));   // pin to AGPR register class
      }
  }
  asm volatile("s_waitcnt vmcnt(0)" ::: "memory");
  __builtin_amdgcn_s_barrier();   // smW visible to all waves (once per dispatch)

  const float br = bhh[j], bz = bhh[1024 + j], bn = bhh[2048 + j];

  auto stageA = [&](const bft* base, int k0, int bufsel) {
    unsigned char* dst = smA + bufsel * 16384;
#pragma unroll
    for (int si = 0; si < 4; ++si) {
      int seg = wid * 4 + si;
      int row = seg * 8 + (lane >> 3);
      int cb = ((lane & 7) * 16) ^ ((row & 7) << 4);
      gl_lds16(base + (long)(m0 + row) * DD + k0 + (cb >> 1), dst + seg * 1024);
    }
  };

  float xg[3][2][4];   // x_proj gate operands for the CURRENT step (prefetched)
  float hp[2][4];      // register-carried fp32 h_prev for this WG's 128x16 slice

  auto prefXG = [&](int s) {
    const long GSTRIDE = (long)BB * 1024;          // one gate plane per step
    long sb_ = (long)s * 3 * GSTRIDE;
#pragma unroll
    for (int mi = 0; mi < 2; ++mi)
#pragma unroll
      for (int r = 0; r < 4; ++r) {
        long b = m0 + wid * 32 + mi * 16 + (lane >> 4) * 4 + r;
        long boff = b * 1024 + j;
        xg[0][mi][r] = (float)xp[sb_ + boff];
        xg[1][mi][r] = (float)xp[sb_ + GSTRIDE + boff];
        xg[2][mi][r] = (float)xp[sb_ + 2 * GSTRIDE + boff];
      }
  };

  prefXG(0);
#pragma unroll
  for (int mi = 0; mi < 2; ++mi)
#pragma unroll
    for (int r = 0; r < 4; ++r) hp[mi][r] = 0.f;
  __builtin_amdgcn_sched_barrier(0);

#pragma unroll 1
  for (int s = 0; s < TT; ++s) {
    if (s) {   // wait for step s-1 producers of my m-group
      int target = pbase + s;
      if (tid < 64) {
        const int* fp = gflags + tid;
        while (ld_co_u32(fp) < target) __builtin_amdgcn_s_sleep(1);
      }
      __syncthreads();
    }

    f32x4 acc[3][2] = {};
    if (s) {                             // t==0: h_prev==0 -> GEMM is zero, skip
      const bft* Ab = hseq + (long)(s - 1) * (BB * (long)DD);
      stageA(Ab, 0, 0);
      stageA(Ab, 64, 1);
      stageA(Ab, 128, 2);
#pragma unroll
      for (int k = 0; k < 16; ++k) {
        __builtin_amdgcn_sched_barrier(0);          // pin: prev reads before stage
        if (k < 13) stageA(Ab, (k + 3) * 64, (k + 3) & 3);
        if (k < 13)       asm volatile("s_waitcnt vmcnt(12)" ::: "memory");
        else if (k == 13) asm volatile("s_waitcnt vmcnt(8)" ::: "memory");
        else if (k == 14) asm volatile("s_waitcnt vmcnt(4)" ::: "memory");
        else              asm volatile("s_waitcnt vmcnt(0)" ::: "memory");
        __builtin_amdgcn_sched_barrier(0);          // pin: reads after vmcnt
        const unsigned char* Abuf = smA + (k & 3) * 16384;
#pragma unroll
        for (int ks = 0; ks < 2; ++ks) {
          int kb = ks * 64 + (lane >> 4) * 16;
          bf16x8 aF[2];
#pragma unroll
          for (int mi = 0; mi < 2; ++mi) {
            int row = wid * 32 + mi * 16 + (lane & 15);
            aF[mi] = *(const bf16x8*)(Abuf + row * 128 + (kb ^ ((row & 7) << 4)));
          }
          int wrow = lane & 15;
          bf16x8 bFn = *(const bf16x8*)(smW + wrow * 2048 +
                                        ((k * 128 + kb) ^ ((wrow & 7) << 4)));
#pragma unroll
          for (int mi = 0; mi < 2; ++mi) {
            acc[0][mi] = __builtin_amdgcn_mfma_f32_16x16x32_bf16(aF[mi], wrz[0][k][ks], acc[0][mi], 0, 0, 0);
            acc[1][mi] = __builtin_amdgcn_mfma_f32_16x16x32_bf16(aF[mi], wrz[1][k][ks], acc[1][mi], 0, 0, 0);
            acc[2][mi] = __builtin_amdgcn_mfma_f32_16x16x32_bf16(aF[mi], bFn,           acc[2][mi], 0, 0, 0);
          }
        }
      }
    }

    // epilogue: GRU cell (h_prev from registers), fast exp2/rcp, WT h stores
    bft* outp = hseq + (long)s * (BB * (long)DD);
#pragma unroll
    for (int mi = 0; mi < 2; ++mi)
#pragma unroll
      for (int r = 0; r < 4; ++r) {
        long b = m0 + wid * 32 + mi * 16 + (lane >> 4) * 4 + r;
        float hr = acc[0][mi][r] + br;
        float hz = acc[1][mi][r] + bz;
        float hn = acc[2][mi][r] + bn;
        float rg = frcp(1.f + fexp2(-LOG2E * (xg[0][mi][r] + hr)));
        float zg = frcp(1.f + fexp2(-LOG2E * (xg[1][mi][r] + hz)));
        float e2 = fexp2(2.f * LOG2E * (xg[2][mi][r] + rg * hn));
        float ng = 1.f - 2.f * frcp(e2 + 1.f);
        float hv = (1.f - zg) * ng + zg * hp[mi][r];
        hp[mi][r] = hv;
        st_wt_bf16(outp + b * DD + j, hv);
      }

    __syncthreads();   // drains each wave's stores (vmcnt0) before flag set
    if (s < TT - 1) {
      if (tid == 0) st_wt_u32(gflags + nt, pbase + s + 1);
      prefXG(s + 1);   // hide xp latency under next step's flag wait
      __builtin_amdgcn_sched_barrier(0);
    }
  }
}

// ---------------- softmax + rebalance (one block per row) ----------------
__device__ __forceinline__ float blk_sum(float v, float* red, int tid) {
#pragma unroll
  for (int o = 32; o; o >>= 1) v += __shfl_xor(v, o);
  if ((tid & 63) == 0) red[tid >> 6] = v;
  __syncthreads();
  v = red[0] + red[1] + red[2] + red[3];
  __syncthreads();
  return v;
}
__device__ __forceinline__ float blk_max(float v, float* red, int tid) {
#pragma unroll
  for (int o = 32; o; o >>= 1) v = fmaxf(v, __shfl_xor(v, o));
  if ((tid & 63) == 0) red[tid >> 6] = v;
  __syncthreads();
  v = fmaxf(fmaxf(red[0], red[1]), fmaxf(red[2], red[3]));
  __syncthreads();
  return v;
}

__launch_bounds__(256)
__global__ void k_smrebal(const float* __restrict__ logits, float* __restrict__ out) {
  __shared__ float red[4];
  const int tid = threadIdx.x;
  const long row = blockIdx.x;
  const float ub = 0.2f, lb = 0.0f;
  float4 lv = *(const float4*)(logits + row * 1024 + tid * 4);

  float m = fmaxf(fmaxf(lv.x, lv.y), fmaxf(lv.z, lv.w));
  m = blk_max(m, red, tid);
  float e[4] = {expf(lv.x - m), expf(lv.y - m), expf(lv.z - m), expf(lv.w - m)};
  float S = blk_sum(e[0] + e[1] + e[2] + e[3], red, tid);

  float old_[4], wc[4];
#pragma unroll
  for (int k = 0; k < 4; ++k) {
    float p = e[k] / S;
    old_[k] = p;
    wc[k] = fminf(fmaxf(p, lb), ub);
  }
  bool done = false;
  for (int it = 0; it < 32 && !done; ++it) {
    float d3 = 0.f, cnt = 0.f, nsum = 0.f;
#pragma unroll
    for (int k = 0; k < 4; ++k) {
      d3 += old_[k] - wc[k];
      bool mk = (wc[k] != ub);
      cnt += mk ? 1.f : 0.f;
      nsum += mk ? wc[k] : 0.f;
    }
    float leftover = blk_sum(d3, red, tid);
    float num = blk_sum(cnt, red, tid);
    float nom_sum = blk_sum(nsum, red, tid);
    float denom = (nom_sum == 0.f) ? 1.f : nom_sum;
    float wcn[4], mx = -1e30f;
#pragma unroll
    for (int k = 0; k < 4; ++k) {
      bool mk = (wc[k] != ub);
      wcn[k] = mk ? wc[k] + leftover * wc[k] / denom : wc[k];
      mx = fmaxf(mx, wcn[k]);
    }
    float gmx = blk_max(mx, red, tid);
    bool no_nom = (num == 0.f);
    bool over = (gmx > ub);
#pragma unroll
    for (int k = 0; k < 4; ++k) {
      float nxt = no_nom ? wc[k] : (over ? fminf(fmaxf(wcn[k], lb), ub) : wcn[k]);
      float oldn = no_nom ? old_[k] : wcn[k];
      wc[k] = nxt;
      old_[k] = oldn;
    }
    done = no_nom || !over;
  }
#pragma unroll
  for (int k = 0; k < 4; ++k) out[row * 1024 + tid * 4 + k] = wc[k];
}

// ---------------- host ----------------
extern "C" void kernel_launch(void* const* d_in, const int* in_sizes, int n_in,
                              void* d_out, int out_size, void* d_ws, size_t ws_size,
                              hipStream_t stream) {
  const float* x      = (const float*)d_in[0];
  const float* wih[2] = {(const float*)d_in[1], (const float*)d_in[5]};
  const float* whh[2] = {(const float*)d_in[2], (const float*)d_in[6]};
  const float* bih[2] = {(const float*)d_in[3], (const float*)d_in[7]};
  const float* bhh[2] = {(const float*)d_in[4], (const float*)d_in[8]};
  const float* fcw    = (const float*)d_in[9];
  const float* fcb    = (const float*)d_in[10];
  float* outp = (float*)d_out;

  unsigned char* ws = (unsigned char*)d_ws;
  size_t off = 0;
  auto alloc = [&](size_t bytes) -> void* {
    void* p = ws + off;
    off += (bytes + 255) & ~(size_t)255;
    return p;
  };
  bft* wihb0   = (bft*)alloc((size_t)G3 * DD * 2);
  bft* whhb0   = (bft*)alloc((size_t)G3 * HH * 2);
  bft* wihb1   = (bft*)alloc((size_t)G3 * HH * 2);
  bft* whhb1   = (bft*)alloc((size_t)G3 * HH * 2);
  bft* fcwb    = (bft*)alloc((size_t)1024 * 1024 * 2);
  bft* xp      = (bft*)alloc((size_t)BB * TT * G3 * 2);       // 403MB x_proj [t][g][b][j]
  bft* hseq0   = (bft*)alloc((size_t)TT * BB * DD * 2);       // 134MB L0 h [t][b][d]
  bft* hseq1   = (bft*)alloc((size_t)TT * BB * DD * 2);       // 134MB L1 h [t][b][d]
  int* flags   = (int*)alloc(1024);                           // 4 groups x 64 slots
  float* logits= (float*)alloc((size_t)BB * 1024 * 4);
  if (off > ws_size) return;  // insufficient workspace: leave output poisoned

  hipMemsetAsync(flags, 0, 1024, stream);

  // weight converts
  k_cvt<<<dim3(1536), dim3(256), 0, stream>>>(wih[0], wihb0, (long)G3 * DD);
  k_cvt<<<dim3(1536), dim3(256), 0, stream>>>(whh[0], whhb0, (long)G3 * HH);
  k_cvt<<<dim3(1536), dim3(256), 0, stream>>>(wih[1], wihb1, (long)G3 * HH);
  k_cvt<<<dim3(1536), dim3(256), 0, stream>>>(whh[1], whhb1, (long)G3 * HH);
  k_cvt<<<dim3(512),  dim3(256), 0, stream>>>(fcw, fcwb, (long)1024 * 1024);

  // L0 x-proj (fused fp32->bf16, xp t-major out): M = 65536, N = 3072, K = 1024
  k_gemm<1, 2, 1><<<dim3(24, 512), 256, 0, stream>>>(
      x, DD, wihb0, DD, bih[0], xp, G3, DD);
  // L0 recurrence: all 128 steps
  k_persist<<<dim3(256), dim3(256), 0, stream>>>(
      whhb0, bhh[0], xp, hseq0, flags, 0);
  // L1 x-proj from hseq0 (t-major in, xp t-major out)
  k_gemm<2, 2, 1><<<dim3(24, 512), 256, 0, stream>>>(
      hseq0, DD, wihb1, DD, bih[1], xp, G3, DD);
  // L1 recurrence
  k_persist<<<dim3(256), dim3(256), 0, stream>>>(
      whhb1, bhh[1], xp, hseq1, flags, TT);

  // FC + SiLU on final h = hseq1[127]
  const bft* hfin = hseq1 + (size_t)(TT - 1) * BB * DD;
  k_gemm<0, 1, 0><<<dim3(1024 / 128, BB / 128), 256, 0, stream>>>(
      hfin, DD, fcwb, HH, fcb, logits, 1024, HH);
  k_smrebal<<<dim3(BB), 256, 0, stream>>>(logits, outp);
}

// Round 14
// 2758.909 us; speedup vs baseline: 1.1163x; 1.1163x over previous
//
#include <hip/hip_runtime.h>
#include <hip/hip_bf16.h>
#include <stdint.h>

// Sizes (fixed by the problem)
#define BB 512      // batch
#define TT 128      // seq len
#define DD 1024     // input dim / hidden
#define HH 1024
#define G3 3072     // 3*H
#define TC 64       // time chunk (r14: 64 -> half the dispatches vs r8)
#define NCH (TT/TC) // 2
#define NRING 65    // ring slots (> TC+1 window -> no address reuse in a dispatch)

typedef __bf16 bft;
typedef __bf16 bf16x8 __attribute__((ext_vector_type(8)));
typedef float f32x4 __attribute__((ext_vector_type(4)));

// async global->LDS, 16B per lane. lds base must be wave-uniform; lane i's data
// lands at base + i*16, so lane i's global ptr must be the data for that slot.
__device__ __forceinline__ void gl_lds16(const bft* g, void* lds_base_uniform) {
  __builtin_amdgcn_global_load_lds(
      (const __attribute__((address_space(1))) void*)g,
      (__attribute__((address_space(3))) void*)lds_base_uniform,
      16, 0, 0);
}

// ---- write-through (sc0 sc1) stores: retire at coherence point ----
__device__ __forceinline__ void st_wt_bf16(bft* p, float v) {
  bft h = (bft)v;
  union { bft h; unsigned short u; } cv; cv.h = h;
  unsigned int uv = cv.u;
  asm volatile("global_store_short %0, %1, off sc0 sc1" :: "v"(p), "v"(uv) : "memory");
}
__device__ __forceinline__ void st_wt_f32(float* p, float v) {
  asm volatile("global_store_dword %0, %1, off sc0 sc1" :: "v"(p), "v"(v) : "memory");
}
__device__ __forceinline__ void st_wt_u32(int* p, int v) {
  asm volatile("global_store_dword %0, %1, off sc0 sc1" :: "v"(p), "v"(v) : "memory");
}
// coherent load (bypass L1/L2 -> always fresh)
__device__ __forceinline__ int ld_co_u32(const int* p) {
  int v;
  asm volatile("global_load_dword %0, %1, off sc0 sc1\n\ts_waitcnt vmcnt(0)"
               : "=v"(v) : "v"(p) : "memory");
  return v;
}

// ---- fast transcendentals (v_exp_f32 = 2^x, v_rcp_f32), ~1ulp ----
__device__ __forceinline__ float fexp2(float x) {
  float r; asm("v_exp_f32 %0, %1" : "=v"(r) : "v"(x)); return r;
}
__device__ __forceinline__ float frcp(float x) {
  float r; asm("v_rcp_f32 %0, %1" : "=v"(r) : "v"(x)); return r;
}
#define LOG2E 1.44269504f

// ---------------- fp32 -> bf16 convert (weights) ----------------
__global__ void k_cvt(const float* __restrict__ in, bft* __restrict__ out, long n) {
  long i = ((long)blockIdx.x * blockDim.x + threadIdx.x) * 8;
  long stride = (long)gridDim.x * blockDim.x * 8;
  for (; i < n; i += stride) {
    float4 a = *(const float4*)(in + i);
    float4 b = *(const float4*)(in + i + 4);
    bf16x8 r;
    r[0] = (bft)a.x; r[1] = (bft)a.y; r[2] = (bft)a.z; r[3] = (bft)a.w;
    r[4] = (bft)b.x; r[5] = (bft)b.y; r[6] = (bft)b.z; r[7] = (bft)b.w;
    *(bf16x8*)(out + i) = r;
  }
}

// ---------------- generic bf16 GEMM: C[m,n] = sum_k A[m,k]*W[n,k] + bias[n] --
// BM=BN=128, BK=64, 256 threads (4 waves 2x2, each wave 64x64 = 4x4 frags).
// AMODE 0: A bf16 packed, row m at A + m*lda.
// AMODE 1: A fp32 = x, chunked: row m -> x[(m>>6)*TT + t0 + (m&63)][*]; staging
//          does fp32 load -> bf16 cvt -> swizzled ds_write (fused gather).
// AMODE 2: A bf16 ring t-major: row m -> slot ((t0s + (m&63)) % NRING), b=m>>6.
// EPI 0: bf16 store. EPI 1: fp32 silu store.
template<int AMODE, int EPI>
__launch_bounds__(256)
__global__ void k_gemm(const void* __restrict__ Ap, long lda,
                       const bft* __restrict__ W, long ldw,
                       const float* __restrict__ bias,
                       void* __restrict__ Cout, long ldc,
                       int t0, int K) {
  __shared__ unsigned char sm[32768];   // A tile 16KB | W tile 16KB
  const int tid  = threadIdx.x;
  const int lane = tid & 63;
  const int wid  = tid >> 6;
  const int m0 = blockIdx.y * 128;
  const int n0 = blockIdx.x * 128;
  const int wm = wid >> 1, wn = wid & 1;

  f32x4 acc[4][4] = {};

  for (int k0 = 0; k0 < K; k0 += 64) {
    if (AMODE == 1) {
      const float* Af = (const float*)Ap;
#pragma unroll
      for (int s = 0; s < 4; ++s) {
        int seg = wid * 4 + s;
        int row = seg * 8 + (lane >> 3);
        int mr = m0 + row;
        long grow = (long)(mr >> 6) * TT + t0 + (mr & 63);
        const float* src = Af + grow * lda + k0 + (lane & 7) * 8;
        float4 a  = *(const float4*)src;
        float4 b2 = *(const float4*)(src + 4);
        bf16x8 r;
        r[0] = (bft)a.x;  r[1] = (bft)a.y;  r[2] = (bft)a.z;  r[3] = (bft)a.w;
        r[4] = (bft)b2.x; r[5] = (bft)b2.y; r[6] = (bft)b2.z; r[7] = (bft)b2.w;
        *(bf16x8*)(sm + seg * 1024 + (lane >> 3) * 128 +
                   (((lane & 7) * 16) ^ ((row & 7) << 4))) = r;
      }
    } else {
      const bft* Ab = (const bft*)Ap;
#pragma unroll
      for (int s = 0; s < 4; ++s) {
        int seg = wid * 4 + s;
        int row = seg * 8 + (lane >> 3);
        int cbs = ((lane & 7) * 16) ^ ((row & 7) << 4);
        int mr = m0 + row;
        long grow;
        if (AMODE == 0) grow = mr;
        else { int sl = t0 + (mr & 63); if (sl >= NRING) sl -= NRING;
               grow = (long)sl * BB + (mr >> 6); }
        gl_lds16(Ab + grow * lda + k0 + (cbs >> 1), sm + seg * 1024);
      }
    }
#pragma unroll
    for (int s = 0; s < 4; ++s) {
      int seg = wid * 4 + s;
      int row = seg * 8 + (lane >> 3);
      int cbs = ((lane & 7) * 16) ^ ((row & 7) << 4);
      gl_lds16(W + (long)(n0 + row) * ldw + k0 + (cbs >> 1), sm + 16384 + seg * 1024);
    }
    __syncthreads();
#pragma unroll
    for (int ks = 0; ks < 2; ++ks) {
      int kb = ks * 64 + (lane >> 4) * 16;
      bf16x8 aF[4], bF[4];
#pragma unroll
      for (int mi = 0; mi < 4; ++mi) {
        int row = wm * 64 + mi * 16 + (lane & 15);
        aF[mi] = *(const bf16x8*)(sm + row * 128 + (kb ^ ((row & 7) << 4)));
      }
#pragma unroll
      for (int ni = 0; ni < 4; ++ni) {
        int row = wn * 64 + ni * 16 + (lane & 15);
        bF[ni] = *(const bf16x8*)(sm + 16384 + row * 128 + (kb ^ ((row & 7) << 4)));
      }
#pragma unroll
      for (int mi = 0; mi < 4; ++mi)
#pragma unroll
        for (int ni = 0; ni < 4; ++ni)
          acc[mi][ni] = __builtin_amdgcn_mfma_f32_16x16x32_bf16(aF[mi], bF[ni], acc[mi][ni], 0, 0, 0);
    }
    __syncthreads();
  }

#pragma unroll
  for (int mi = 0; mi < 4; ++mi)
#pragma unroll
    for (int ni = 0; ni < 4; ++ni) {
      int col = n0 + wn * 64 + ni * 16 + (lane & 15);
      float bv = bias[col];
#pragma unroll
      for (int r = 0; r < 4; ++r) {
        long row = m0 + wm * 64 + mi * 16 + (lane >> 4) * 4 + r;
        float v = acc[mi][ni][r] + bv;
        if (EPI == 0) {
          ((bft*)Cout)[row * ldc + col] = (bft)v;
        } else {
          ((float*)Cout)[row * ldc + col] = v / (1.f + expf(-v));
        }
      }
    }
}

// ---------------- persistent GRU chunk kernel ----------------
// 256 WGs = 4 m-groups (XCD pairs) x 64 j-tiles, 1 WG/CU (4 waves, 1/SIMD).
// W_hh r,z gates pinned in AGPRs (256/wave); n gate (16x1024, 32KB swizzled)
// in LDS. A (h_prev 128x1024 bf16) staged via 4-deep LDS pipeline, counted
// vmcnt. h fp32 carried in registers across steps. h written per step to a
// FRESH ring slot (65) via write-through stores; per-WG flag after; consumers
// poll their m-group's 64 flags. No cache fences.
__launch_bounds__(256, 1)
__global__ void k_persist(const bft* __restrict__ whh, const float* __restrict__ bhh,
                          const bft* __restrict__ xp,
                          bft* __restrict__ ring,     // [NRING][BB][DD]
                          float* __restrict__ hfc, int* __restrict__ flags,
                          int t0s, int first, int pbase) {
  __shared__ unsigned char sm[98304];           // W_n 32KB | A 4x16KB
  unsigned char* smW = sm;
  unsigned char* smA = sm + 32768;

  const int tid  = threadIdx.x;
  const int lane = tid & 63;
  const int wid  = tid >> 6;
  const int bid  = blockIdx.x;
  const int xcd = bid & 7, loc = bid >> 3;
  const int mt = xcd >> 1;                // m-group = XCD pair
  const int nt = (xcd & 1) * 32 + loc;    // 0..63 j-tile within group
  const int j0 = nt * 16;
  const int m0 = mt * 128;
  const int j  = j0 + (lane & 15);
  int* gflags = flags + mt * 64;

  // ---- n-gate W slice into LDS (16 rows x 2048B, XOR-swizzled source)
#pragma unroll
  for (int s8 = 0; s8 < 8; ++s8) {
    int s = wid * 8 + s8;
    int row = s >> 1;
    int half = s & 1;
    int hb = half * 1024 + lane * 16;
    int sb = hb ^ ((row & 7) << 4);
    long grow = (long)(2 * 1024 + j0 + row);
    gl_lds16(whh + grow * 1024 + (sb >> 1), smW + s * 1024);
  }

  // ---- r,z gate W slice into AGPRs: 64 bf16x8 frags, pinned via "a" class
  bf16x8 wrz[2][16][2];
#pragma unroll
  for (int g = 0; g < 2; ++g) {
    const bft* wbase = whh + (((long)g * 1024 + j) << 10) + ((lane >> 4) * 8);
#pragma unroll
    for (int k = 0; k < 16; ++k)
#pragma unroll
      for (int ks = 0; ks < 2; ++ks) {
        bf16x8 wl = *(const bf16x8*)(wbase + k * 64 + ks * 32);
        asm("" : "=a"(wrz[g][k][ks]) : "0"(wl));   // pin to AGPR register class
      }
  }
  asm volatile("s_waitcnt vmcnt(0)" ::: "memory");
  __builtin_amdgcn_s_barrier();

  const float br = bhh[j], bz = bhh[1024 + j], bn = bhh[2048 + j];

  auto stageA = [&](const bft* base, int k0, int bufsel) {
    unsigned char* dst = smA + bufsel * 16384;
#pragma unroll
    for (int si = 0; si < 4; ++si) {
      int seg = wid * 4 + si;
      int row = seg * 8 + (lane >> 3);
      int cb = ((lane & 7) * 16) ^ ((row & 7) << 4);
      gl_lds16(base + (long)(m0 + row) * DD + k0 + (cb >> 1), dst + seg * 1024);
    }
  };

  float xg[3][2][4];   // x_proj gate operands for the CURRENT step (prefetched)
  float hp[2][4];      // register-carried fp32 h_prev for this WG's 128x16 slice

  auto prefXG = [&](int s) {
#pragma unroll
    for (int mi = 0; mi < 2; ++mi)
#pragma unroll
      for (int r = 0; r < 4; ++r) {
        long b = m0 + wid * 32 + mi * 16 + (lane >> 4) * 4 + r;
        long xrow = (b * TC + s) * (long)G3 + j;
        xg[0][mi][r] = (float)xp[xrow];
        xg[1][mi][r] = (float)xp[xrow + 1024];
        xg[2][mi][r] = (float)xp[xrow + 2048];
      }
  };

  prefXG(0);
  if (first) {
#pragma unroll
    for (int mi = 0; mi < 2; ++mi)
#pragma unroll
      for (int r = 0; r < 4; ++r) hp[mi][r] = 0.f;
  } else {
#pragma unroll
    for (int mi = 0; mi < 2; ++mi)
#pragma unroll
      for (int r = 0; r < 4; ++r) {
        long b = m0 + wid * 32 + mi * 16 + (lane >> 4) * 4 + r;
        hp[mi][r] = hfc[b * HH + j];
      }
  }
  __builtin_amdgcn_sched_barrier(0);

  for (int s = 0; s < TC; ++s) {
    if (s) {   // wait for step s-1 producers of my m-group
      int target = pbase + s;
      if (tid < 64) {
        const int* fp = gflags + tid;
        while (ld_co_u32(fp) < target) __builtin_amdgcn_s_sleep(2);
      }
      __syncthreads();
    }

    int sl = t0s + s; if (sl >= NRING) sl -= NRING;
    int psl = sl ? sl - 1 : NRING - 1;

    f32x4 acc[3][2] = {};
    if (!(first && s == 0)) {            // t==0: h_prev==0 -> GEMM is zero, skip
      const bft* Ab = ring + (long)psl * (BB * (long)DD);
      stageA(Ab, 0, 0);
      stageA(Ab, 64, 1);
      stageA(Ab, 128, 2);
#pragma unroll
      for (int k = 0; k < 16; ++k) {
        __builtin_amdgcn_s_barrier();               // prev-iter LDS reads done
        if (k < 13) stageA(Ab, (k + 3) * 64, (k + 3) & 3);
        if (k < 13)       asm volatile("s_waitcnt vmcnt(12)" ::: "memory");
        else if (k == 13) asm volatile("s_waitcnt vmcnt(8)" ::: "memory");
        else if (k == 14) asm volatile("s_waitcnt vmcnt(4)" ::: "memory");
        else              asm volatile("s_waitcnt vmcnt(0)" ::: "memory");
        __builtin_amdgcn_s_barrier();               // stage(k) visible to all waves
        __builtin_amdgcn_sched_barrier(0);
        const unsigned char* Abuf = smA + (k & 3) * 16384;
#pragma unroll
        for (int ks = 0; ks < 2; ++ks) {
          int kb = ks * 64 + (lane >> 4) * 16;
          bf16x8 aF[2];
#pragma unroll
          for (int mi = 0; mi < 2; ++mi) {
            int row = wid * 32 + mi * 16 + (lane & 15);
            aF[mi] = *(const bf16x8*)(Abuf + row * 128 + (kb ^ ((row & 7) << 4)));
          }
          int wrow = lane & 15;
          bf16x8 bFn = *(const bf16x8*)(smW + wrow * 2048 +
                                        ((k * 128 + kb) ^ ((wrow & 7) << 4)));
#pragma unroll
          for (int mi = 0; mi < 2; ++mi) {
            acc[0][mi] = __builtin_amdgcn_mfma_f32_16x16x32_bf16(aF[mi], wrz[0][k][ks], acc[0][mi], 0, 0, 0);
            acc[1][mi] = __builtin_amdgcn_mfma_f32_16x16x32_bf16(aF[mi], wrz[1][k][ks], acc[1][mi], 0, 0, 0);
            acc[2][mi] = __builtin_amdgcn_mfma_f32_16x16x32_bf16(aF[mi], bFn,           acc[2][mi], 0, 0, 0);
          }
        }
      }
    }

    // epilogue: GRU cell (h_prev from registers), fast exp2/rcp, WT h stores
    bft* outp = ring + (long)sl * (BB * (long)DD);
#pragma unroll
    for (int mi = 0; mi < 2; ++mi)
#pragma unroll
      for (int r = 0; r < 4; ++r) {
        long b = m0 + wid * 32 + mi * 16 + (lane >> 4) * 4 + r;
        float hr = acc[0][mi][r] + br;
        float hz = acc[1][mi][r] + bz;
        float hn = acc[2][mi][r] + bn;
        float rg = frcp(1.f + fexp2(-LOG2E * (xg[0][mi][r] + hr)));
        float zg = frcp(1.f + fexp2(-LOG2E * (xg[1][mi][r] + hz)));
        float e2 = fexp2(2.f * LOG2E * (xg[2][mi][r] + rg * hn));
        float ng = 1.f - 2.f * frcp(e2 + 1.f);
        float hv = (1.f - zg) * ng + zg * hp[mi][r];
        hp[mi][r] = hv;
        st_wt_bf16(outp + b * DD + j, hv);
        if (s == TC - 1) st_wt_f32(hfc + b * HH + j, hv);
      }

    __syncthreads();   // drains each wave's stores (vmcnt0) before flag set
    if (s < TC - 1) {
      if (tid == 0) st_wt_u32(gflags + nt, pbase + s + 1);
      prefXG(s + 1);   // hide xp latency under next step's flag wait
      __builtin_amdgcn_sched_barrier(0);
    }
  }
}

// ---------------- softmax + rebalance (one block per row) ----------------
__device__ __forceinline__ float blk_sum(float v, float* red, int tid) {
#pragma unroll
  for (int o = 32; o; o >>= 1) v += __shfl_xor(v, o);
  if ((tid & 63) == 0) red[tid >> 6] = v;
  __syncthreads();
  v = red[0] + red[1] + red[2] + red[3];
  __syncthreads();
  return v;
}
__device__ __forceinline__ float blk_max(float v, float* red, int tid) {
#pragma unroll
  for (int o = 32; o; o >>= 1) v = fmaxf(v, __shfl_xor(v, o));
  if ((tid & 63) == 0) red[tid >> 6] = v;
  __syncthreads();
  v = fmaxf(fmaxf(red[0], red[1]), fmaxf(red[2], red[3]));
  __syncthreads();
  return v;
}

__launch_bounds__(256)
__global__ void k_smrebal(const float* __restrict__ logits, float* __restrict__ out) {
  __shared__ float red[4];
  const int tid = threadIdx.x;
  const long row = blockIdx.x;
  const float ub = 0.2f, lb = 0.0f;
  float4 lv = *(const float4*)(logits + row * 1024 + tid * 4);

  float m = fmaxf(fmaxf(lv.x, lv.y), fmaxf(lv.z, lv.w));
  m = blk_max(m, red, tid);
  float e[4] = {expf(lv.x - m), expf(lv.y - m), expf(lv.z - m), expf(lv.w - m)};
  float S = blk_sum(e[0] + e[1] + e[2] + e[3], red, tid);

  float old_[4], wc[4];
#pragma unroll
  for (int k = 0; k < 4; ++k) {
    float p = e[k] / S;
    old_[k] = p;
    wc[k] = fminf(fmaxf(p, lb), ub);
  }
  bool done = false;
  for (int it = 0; it < 32 && !done; ++it) {
    float d3 = 0.f, cnt = 0.f, nsum = 0.f;
#pragma unroll
    for (int k = 0; k < 4; ++k) {
      d3 += old_[k] - wc[k];
      bool mk = (wc[k] != ub);
      cnt += mk ? 1.f : 0.f;
      nsum += mk ? wc[k] : 0.f;
    }
    float leftover = blk_sum(d3, red, tid);
    float num = blk_sum(cnt, red, tid);
    float nom_sum = blk_sum(nsum, red, tid);
    float denom = (nom_sum == 0.f) ? 1.f : nom_sum;
    float wcn[4], mx = -1e30f;
#pragma unroll
    for (int k = 0; k < 4; ++k) {
      bool mk = (wc[k] != ub);
      wcn[k] = mk ? wc[k] + leftover * wc[k] / denom : wc[k];
      mx = fmaxf(mx, wcn[k]);
    }
    float gmx = blk_max(mx, red, tid);
    bool no_nom = (num == 0.f);
    bool over = (gmx > ub);
#pragma unroll
    for (int k = 0; k < 4; ++k) {
      float nxt = no_nom ? wc[k] : (over ? fminf(fmaxf(wcn[k], lb), ub) : wcn[k]);
      float oldn = no_nom ? old_[k] : wcn[k];
      wc[k] = nxt;
      old_[k] = oldn;
    }
    done = no_nom || !over;
  }
#pragma unroll
  for (int k = 0; k < 4; ++k) out[row * 1024 + tid * 4 + k] = wc[k];
}

// ---------------- host ----------------
extern "C" void kernel_launch(void* const* d_in, const int* in_sizes, int n_in,
                              void* d_out, int out_size, void* d_ws, size_t ws_size,
                              hipStream_t stream) {
  const float* x      = (const float*)d_in[0];
  const float* wih[2] = {(const float*)d_in[1], (const float*)d_in[5]};
  const float* whh[2] = {(const float*)d_in[2], (const float*)d_in[6]};
  const float* bih[2] = {(const float*)d_in[3], (const float*)d_in[7]};
  const float* bhh[2] = {(const float*)d_in[4], (const float*)d_in[8]};
  const float* fcw    = (const float*)d_in[9];
  const float* fcb    = (const float*)d_in[10];
  float* outp = (float*)d_out;

  unsigned char* ws = (unsigned char*)d_ws;
  size_t off = 0;
  auto alloc = [&](size_t bytes) -> void* {
    void* p = ws + off;
    off += (bytes + 255) & ~(size_t)255;
    return p;
  };
  bft* wihb0   = (bft*)alloc((size_t)G3 * DD * 2);
  bft* whhb0   = (bft*)alloc((size_t)G3 * HH * 2);
  bft* wihb1   = (bft*)alloc((size_t)G3 * HH * 2);
  bft* whhb1   = (bft*)alloc((size_t)G3 * HH * 2);
  bft* fcwb    = (bft*)alloc((size_t)1024 * 1024 * 2);
  bft* xp      = (bft*)alloc((size_t)BB * TC * G3 * 2);       // 201MB chunk x_proj
  bft* ring0   = (bft*)alloc((size_t)NRING * BB * DD * 2);    // 68MB L0 h ring
  bft* ring1   = (bft*)alloc((size_t)NRING * BB * DD * 2);    // 68MB L1 h ring
  float* hfc0  = (float*)alloc((size_t)BB * HH * 4);          // L0 chunk-boundary h
  float* hfc1  = (float*)alloc((size_t)BB * HH * 4);          // L1 chunk-boundary h
  int* flags   = (int*)alloc(1024);                           // 4 groups x 64 slots
  float* logits= (float*)alloc((size_t)BB * 1024 * 4);
  if (off > ws_size) return;  // insufficient workspace: leave output poisoned

  hipMemsetAsync(flags, 0, 1024, stream);

  // weight converts
  k_cvt<<<dim3(1536), dim3(256), 0, stream>>>(wih[0], wihb0, (long)G3 * DD);
  k_cvt<<<dim3(1536), dim3(256), 0, stream>>>(whh[0], whhb0, (long)G3 * HH);
  k_cvt<<<dim3(1536), dim3(256), 0, stream>>>(wih[1], wihb1, (long)G3 * HH);
  k_cvt<<<dim3(1536), dim3(256), 0, stream>>>(whh[1], whhb1, (long)G3 * HH);
  k_cvt<<<dim3(512),  dim3(256), 0, stream>>>(fcw, fcwb, (long)1024 * 1024);

  for (int c = 0; c < NCH; ++c) {
    int t0 = c * TC;
    int t0s = t0 % NRING;
    int first = (c == 0) ? 1 : 0;
    // L0 x-proj (fused x gather+convert): M = BB*TC = 32768, N = 3072, K = 1024
    k_gemm<1, 0><<<dim3(G3 / 128, (BB * TC) / 128), 256, 0, stream>>>(
        x, DD, wihb0, DD, bih[0], xp, G3, t0, DD);
    k_persist<<<dim3(256), dim3(256), 0, stream>>>(
        whhb0, bhh[0], xp, ring0, hfc0, flags, t0s, first, (2 * c) * TC);
    // L1 x-proj from ring0 (t-major slots)
    k_gemm<2, 0><<<dim3(G3 / 128, (BB * TC) / 128), 256, 0, stream>>>(
        ring0, DD, wihb1, DD, bih[1], xp, G3, t0s, DD);
    k_persist<<<dim3(256), dim3(256), 0, stream>>>(
        whhb1, bhh[1], xp, ring1, hfc1, flags, t0s, first, (2 * c + 1) * TC);
  }
  // FC + SiLU on final h: t=127 -> ring1 slot 127%65 = 62
  const bft* hfin = ring1 + (size_t)((TT - 1) % NRING) * BB * DD;
  k_gemm<0, 1><<<dim3(1024 / 128, BB / 128), 256, 0, stream>>>(
      hfin, DD, fcwb, HH, fcb, logits, 1024, 0, HH);
  k_smrebal<<<dim3(BB), 256, 0, stream>>>(logits, outp);
}

// Round 15
// 2673.026 us; speedup vs baseline: 1.1521x; 1.0321x over previous
//
#include <hip/hip_runtime.h>
#include <hip/hip_bf16.h>
#include <stdint.h>

// Sizes (fixed by the problem)
#define BB 512      // batch
#define TT 128      // seq len
#define DD 1024     // input dim / hidden
#define HH 1024
#define G3 3072     // 3*H
#define TC 32       // time chunk
#define NCH (TT/TC) // 4
#define NRING 33    // ring slots (> TC+1 window -> no address reuse in a dispatch)

typedef __bf16 bft;
typedef __bf16 bf16x8 __attribute__((ext_vector_type(8)));
typedef float f32x4 __attribute__((ext_vector_type(4)));

// async global->LDS, 16B per lane. lds base must be wave-uniform; lane i's data
// lands at base + i*16, so lane i's global ptr must be the data for that slot.
__device__ __forceinline__ void gl_lds16(const bft* g, void* lds_base_uniform) {
  __builtin_amdgcn_global_load_lds(
      (const __attribute__((address_space(1))) void*)g,
      (__attribute__((address_space(3))) void*)lds_base_uniform,
      16, 0, 0);
}

// ---- write-through (sc0 sc1) stores: retire at coherence point ----
__device__ __forceinline__ void st_wt_bf16(bft* p, float v) {
  bft h = (bft)v;
  union { bft h; unsigned short u; } cv; cv.h = h;
  unsigned int uv = cv.u;
  asm volatile("global_store_short %0, %1, off sc0 sc1" :: "v"(p), "v"(uv) : "memory");
}
__device__ __forceinline__ void st_wt_f32(float* p, float v) {
  asm volatile("global_store_dword %0, %1, off sc0 sc1" :: "v"(p), "v"(v) : "memory");
}
__device__ __forceinline__ void st_wt_u32(int* p, int v) {
  asm volatile("global_store_dword %0, %1, off sc0 sc1" :: "v"(p), "v"(v) : "memory");
}
// coherent load (bypass L1/L2 -> always fresh)
__device__ __forceinline__ int ld_co_u32(const int* p) {
  int v;
  asm volatile("global_load_dword %0, %1, off sc0 sc1\n\ts_waitcnt vmcnt(0)"
               : "=v"(v) : "v"(p) : "memory");
  return v;
}

// ---- fast transcendentals (v_exp_f32 = 2^x, v_rcp_f32), ~1ulp ----
__device__ __forceinline__ float fexp2(float x) {
  float r; asm("v_exp_f32 %0, %1" : "=v"(r) : "v"(x)); return r;
}
__device__ __forceinline__ float frcp(float x) {
  float r; asm("v_rcp_f32 %0, %1" : "=v"(r) : "v"(x)); return r;
}
#define LOG2E 1.44269504f

// ---------------- fp32 -> bf16 convert (weights) ----------------
__global__ void k_cvt(const float* __restrict__ in, bft* __restrict__ out, long n) {
  long i = ((long)blockIdx.x * blockDim.x + threadIdx.x) * 8;
  long stride = (long)gridDim.x * blockDim.x * 8;
  for (; i < n; i += stride) {
    float4 a = *(const float4*)(in + i);
    float4 b = *(const float4*)(in + i + 4);
    bf16x8 r;
    r[0] = (bft)a.x; r[1] = (bft)a.y; r[2] = (bft)a.z; r[3] = (bft)a.w;
    r[4] = (bft)b.x; r[5] = (bft)b.y; r[6] = (bft)b.z; r[7] = (bft)b.w;
    *(bf16x8*)(out + i) = r;
  }
}

// ---------------- generic bf16 GEMM: C[m,n] = sum_k A[m,k]*W[n,k] + bias[n] --
// BM=BN=128, BK=64, 256 threads (4 waves 2x2, each wave 64x64 = 4x4 frags).
// AMODE 0: A bf16 packed, row m at A + m*lda.
// AMODE 1: A fp32 = x, chunked: row m -> x[(m>>5)*TT + t0 + (m&31)][*]; staging
//          does fp32 load -> bf16 cvt -> swizzled ds_write (fused gather).
// AMODE 2: A bf16 ring t-major: row m -> slot ((t0s + (m&31)) % NRING), b=m>>5.
// EPI 0: bf16 store. EPI 1: fp32 silu store.
template<int AMODE, int EPI>
__launch_bounds__(256)
__global__ void k_gemm(const void* __restrict__ Ap, long lda,
                       const bft* __restrict__ W, long ldw,
                       const float* __restrict__ bias,
                       void* __restrict__ Cout, long ldc,
                       int t0, int K) {
  __shared__ unsigned char sm[32768];   // A tile 16KB | W tile 16KB
  const int tid  = threadIdx.x;
  const int lane = tid & 63;
  const int wid  = tid >> 6;
  const int m0 = blockIdx.y * 128;
  const int n0 = blockIdx.x * 128;
  const int wm = wid >> 1, wn = wid & 1;

  f32x4 acc[4][4] = {};

  for (int k0 = 0; k0 < K; k0 += 64) {
    if (AMODE == 1) {
      const float* Af = (const float*)Ap;
#pragma unroll
      for (int s = 0; s < 4; ++s) {
        int seg = wid * 4 + s;
        int row = seg * 8 + (lane >> 3);
        int mr = m0 + row;
        long grow = (long)(mr >> 5) * TT + t0 + (mr & 31);
        const float* src = Af + grow * lda + k0 + (lane & 7) * 8;
        float4 a  = *(const float4*)src;
        float4 b2 = *(const float4*)(src + 4);
        bf16x8 r;
        r[0] = (bft)a.x;  r[1] = (bft)a.y;  r[2] = (bft)a.z;  r[3] = (bft)a.w;
        r[4] = (bft)b2.x; r[5] = (bft)b2.y; r[6] = (bft)b2.z; r[7] = (bft)b2.w;
        *(bf16x8*)(sm + seg * 1024 + (lane >> 3) * 128 +
                   (((lane & 7) * 16) ^ ((row & 7) << 4))) = r;
      }
    } else {
      const bft* Ab = (const bft*)Ap;
#pragma unroll
      for (int s = 0; s < 4; ++s) {
        int seg = wid * 4 + s;
        int row = seg * 8 + (lane >> 3);
        int cbs = ((lane & 7) * 16) ^ ((row & 7) << 4);
        int mr = m0 + row;
        long grow;
        if (AMODE == 0) grow = mr;
        else { int sl = t0 + (mr & 31); if (sl >= NRING) sl -= NRING;
               grow = (long)sl * BB + (mr >> 5); }
        gl_lds16(Ab + grow * lda + k0 + (cbs >> 1), sm + seg * 1024);
      }
    }
#pragma unroll
    for (int s = 0; s < 4; ++s) {
      int seg = wid * 4 + s;
      int row = seg * 8 + (lane >> 3);
      int cbs = ((lane & 7) * 16) ^ ((row & 7) << 4);
      gl_lds16(W + (long)(n0 + row) * ldw + k0 + (cbs >> 1), sm + 16384 + seg * 1024);
    }
    __syncthreads();
#pragma unroll
    for (int ks = 0; ks < 2; ++ks) {
      int kb = ks * 64 + (lane >> 4) * 16;
      bf16x8 aF[4], bF[4];
#pragma unroll
      for (int mi = 0; mi < 4; ++mi) {
        int row = wm * 64 + mi * 16 + (lane & 15);
        aF[mi] = *(const bf16x8*)(sm + row * 128 + (kb ^ ((row & 7) << 4)));
      }
#pragma unroll
      for (int ni = 0; ni < 4; ++ni) {
        int row = wn * 64 + ni * 16 + (lane & 15);
        bF[ni] = *(const bf16x8*)(sm + 16384 + row * 128 + (kb ^ ((row & 7) << 4)));
      }
#pragma unroll
      for (int mi = 0; mi < 4; ++mi)
#pragma unroll
        for (int ni = 0; ni < 4; ++ni)
          acc[mi][ni] = __builtin_amdgcn_mfma_f32_16x16x32_bf16(aF[mi], bF[ni], acc[mi][ni], 0, 0, 0);
    }
    __syncthreads();
  }

#pragma unroll
  for (int mi = 0; mi < 4; ++mi)
#pragma unroll
    for (int ni = 0; ni < 4; ++ni) {
      int col = n0 + wn * 64 + ni * 16 + (lane & 15);
      float bv = bias[col];
#pragma unroll
      for (int r = 0; r < 4; ++r) {
        long row = m0 + wm * 64 + mi * 16 + (lane >> 4) * 4 + r;
        float v = acc[mi][ni][r] + bv;
        if (EPI == 0) {
          ((bft*)Cout)[row * ldc + col] = (bft)v;
        } else {
          ((float*)Cout)[row * ldc + col] = v / (1.f + expf(-v));
        }
      }
    }
}

// ---------------- persistent GRU chunk kernel ----------------
// 256 WGs = 4 m-groups (XCD pairs) x 64 j-tiles, 1 WG/CU (4 waves, 1/SIMD).
// W_hh r,z gates pinned in AGPRs (256/wave via "a" constraint; gfx950 MFMA
// B-operand is AV-class so no per-use copies); n gate (16x1024, 32KB swizzled)
// in LDS. A (h_prev 128x1024 bf16) staged via 4-deep LDS pipeline, counted
// vmcnt. h fp32 carried in registers across steps. h written per step to a
// FRESH ring slot (33) via write-through stores; per-WG flag after; consumers
// poll their m-group's 64 flags. No cache fences.
__launch_bounds__(256, 1)
__global__ void k_persist(const bft* __restrict__ whh, const float* __restrict__ bhh,
                          const bft* __restrict__ xp,
                          bft* __restrict__ ring,     // [NRING][BB][DD]
                          float* __restrict__ hfc, int* __restrict__ flags,
                          int t0s, int first, int pbase) {
  __shared__ unsigned char sm[98304];           // W_n 32KB | A 4x16KB
  unsigned char* smW = sm;
  unsigned char* smA = sm + 32768;

  const int tid  = threadIdx.x;
  const int lane = tid & 63;
  const int wid  = tid >> 6;
  const int bid  = blockIdx.x;
  const int xcd = bid & 7, loc = bid >> 3;
  const int mt = xcd >> 1;                // m-group = XCD pair
  const int nt = (xcd & 1) * 32 + loc;    // 0..63 j-tile within group
  const int j0 = nt * 16;
  const int m0 = mt * 128;
  const int j  = j0 + (lane & 15);
  int* gflags = flags + mt * 64;

  // ---- n-gate W slice into LDS (16 rows x 2048B, XOR-swizzled source)
#pragma unroll
  for (int s8 = 0; s8 < 8; ++s8) {
    int s = wid * 8 + s8;
    int row = s >> 1;
    int half = s & 1;
    int hb = half * 1024 + lane * 16;
    int sb = hb ^ ((row & 7) << 4);
    long grow = (long)(2 * 1024 + j0 + row);
    gl_lds16(whh + grow * 1024 + (sb >> 1), smW + s * 1024);
  }

  // ---- r,z gate W slice into AGPRs: 64 bf16x8 frags, pinned via "a" class
  bf16x8 wrz[2][16][2];
#pragma unroll
  for (int g = 0; g < 2; ++g) {
    const bft* wbase = whh + (((long)g * 1024 + j) << 10) + ((lane >> 4) * 8);
#pragma unroll
    for (int k = 0; k < 16; ++k)
#pragma unroll
      for (int ks = 0; ks < 2; ++ks) {
        bf16x8 wl = *(const bf16x8*)(wbase + k * 64 + ks * 32);
        asm("" : "=a"(wrz[g][k][ks]) : "0"(wl));   // pin to AGPR register class
      }
  }
  asm volatile("s_waitcnt vmcnt(0)" ::: "memory");
  __builtin_amdgcn_s_barrier();

  const float br = bhh[j], bz = bhh[1024 + j], bn = bhh[2048 + j];

  auto stageA = [&](const bft* base, int k0, int bufsel) {
    unsigned char* dst = smA + bufsel * 16384;
#pragma unroll
    for (int si = 0; si < 4; ++si) {
      int seg = wid * 4 + si;
      int row = seg * 8 + (lane >> 3);
      int cb = ((lane & 7) * 16) ^ ((row & 7) << 4);
      gl_lds16(base + (long)(m0 + row) * DD + k0 + (cb >> 1), dst + seg * 1024);
    }
  };

  float xg[3][2][4];   // x_proj gate operands for the CURRENT step (prefetched)
  float hp[2][4];      // register-carried fp32 h_prev for this WG's 128x16 slice

  auto prefXG = [&](int s) {
#pragma unroll
    for (int mi = 0; mi < 2; ++mi)
#pragma unroll
      for (int r = 0; r < 4; ++r) {
        long b = m0 + wid * 32 + mi * 16 + (lane >> 4) * 4 + r;
        long xrow = (b * TC + s) * (long)G3 + j;
        xg[0][mi][r] = (float)xp[xrow];
        xg[1][mi][r] = (float)xp[xrow + 1024];
        xg[2][mi][r] = (float)xp[xrow + 2048];
      }
  };

  prefXG(0);
  if (first) {
#pragma unroll
    for (int mi = 0; mi < 2; ++mi)
#pragma unroll
      for (int r = 0; r < 4; ++r) hp[mi][r] = 0.f;
  } else {
#pragma unroll
    for (int mi = 0; mi < 2; ++mi)
#pragma unroll
      for (int r = 0; r < 4; ++r) {
        long b = m0 + wid * 32 + mi * 16 + (lane >> 4) * 4 + r;
        hp[mi][r] = hfc[b * HH + j];
      }
  }
  __builtin_amdgcn_sched_barrier(0);

  for (int s = 0; s < TC; ++s) {
    if (s) {   // wait for step s-1 producers of my m-group
      int target = pbase + s;
      if (tid < 64) {
        const int* fp = gflags + tid;
        while (ld_co_u32(fp) < target) __builtin_amdgcn_s_sleep(2);
      }
      __syncthreads();
    }

    int sl = t0s + s; if (sl >= NRING) sl -= NRING;
    int psl = sl ? sl - 1 : NRING - 1;

    f32x4 acc[3][2] = {};
    if (!(first && s == 0)) {            // t==0: h_prev==0 -> GEMM is zero, skip
      const bft* Ab = ring + (long)psl * (BB * (long)DD);
      stageA(Ab, 0, 0);
      stageA(Ab, 64, 1);
      stageA(Ab, 128, 2);
#pragma unroll
      for (int k = 0; k < 16; ++k) {
        __builtin_amdgcn_s_barrier();               // prev-iter LDS reads done
        if (k < 13) stageA(Ab, (k + 3) * 64, (k + 3) & 3);
        if (k < 13)       asm volatile("s_waitcnt vmcnt(12)" ::: "memory");
        else if (k == 13) asm volatile("s_waitcnt vmcnt(8)" ::: "memory");
        else if (k == 14) asm volatile("s_waitcnt vmcnt(4)" ::: "memory");
        else              asm volatile("s_waitcnt vmcnt(0)" ::: "memory");
        __builtin_amdgcn_s_barrier();               // stage(k) visible to all waves
        __builtin_amdgcn_sched_barrier(0);
        const unsigned char* Abuf = smA + (k & 3) * 16384;
#pragma unroll
        for (int ks = 0; ks < 2; ++ks) {
          int kb = ks * 64 + (lane >> 4) * 16;
          bf16x8 aF[2];
#pragma unroll
          for (int mi = 0; mi < 2; ++mi) {
            int row = wid * 32 + mi * 16 + (lane & 15);
            aF[mi] = *(const bf16x8*)(Abuf + row * 128 + (kb ^ ((row & 7) << 4)));
          }
          int wrow = lane & 15;
          bf16x8 bFn = *(const bf16x8*)(smW + wrow * 2048 +
                                        ((k * 128 + kb) ^ ((wrow & 7) << 4)));
#pragma unroll
          for (int mi = 0; mi < 2; ++mi) {
            acc[0][mi] = __builtin_amdgcn_mfma_f32_16x16x32_bf16(aF[mi], wrz[0][k][ks], acc[0][mi], 0, 0, 0);
            acc[1][mi] = __builtin_amdgcn_mfma_f32_16x16x32_bf16(aF[mi], wrz[1][k][ks], acc[1][mi], 0, 0, 0);
            acc[2][mi] = __builtin_amdgcn_mfma_f32_16x16x32_bf16(aF[mi], bFn,           acc[2][mi], 0, 0, 0);
          }
        }
      }
    }

    // epilogue: GRU cell (h_prev from registers), fast exp2/rcp, WT h stores
    bft* outp = ring + (long)sl * (BB * (long)DD);
#pragma unroll
    for (int mi = 0; mi < 2; ++mi)
#pragma unroll
      for (int r = 0; r < 4; ++r) {
        long b = m0 + wid * 32 + mi * 16 + (lane >> 4) * 4 + r;
        float hr = acc[0][mi][r] + br;
        float hz = acc[1][mi][r] + bz;
        float hn = acc[2][mi][r] + bn;
        float rg = frcp(1.f + fexp2(-LOG2E * (xg[0][mi][r] + hr)));
        float zg = frcp(1.f + fexp2(-LOG2E * (xg[1][mi][r] + hz)));
        float e2 = fexp2(2.f * LOG2E * (xg[2][mi][r] + rg * hn));
        float ng = 1.f - 2.f * frcp(e2 + 1.f);
        float hv = (1.f - zg) * ng + zg * hp[mi][r];
        hp[mi][r] = hv;
        st_wt_bf16(outp + b * DD + j, hv);
        if (s == TC - 1) st_wt_f32(hfc + b * HH + j, hv);
      }

    __syncthreads();   // drains each wave's stores (vmcnt0) before flag set
    if (s < TC - 1) {
      if (tid == 0) st_wt_u32(gflags + nt, pbase + s + 1);
      prefXG(s + 1);   // hide xp latency under next step's flag wait
      __builtin_amdgcn_sched_barrier(0);
    }
  }
}

// ---------------- softmax + rebalance (one block per row) ----------------
__device__ __forceinline__ float blk_sum(float v, float* red, int tid) {
#pragma unroll
  for (int o = 32; o; o >>= 1) v += __shfl_xor(v, o);
  if ((tid & 63) == 0) red[tid >> 6] = v;
  __syncthreads();
  v = red[0] + red[1] + red[2] + red[3];
  __syncthreads();
  return v;
}
__device__ __forceinline__ float blk_max(float v, float* red, int tid) {
#pragma unroll
  for (int o = 32; o; o >>= 1) v = fmaxf(v, __shfl_xor(v, o));
  if ((tid & 63) == 0) red[tid >> 6] = v;
  __syncthreads();
  v = fmaxf(fmaxf(red[0], red[1]), fmaxf(red[2], red[3]));
  __syncthreads();
  return v;
}

__launch_bounds__(256)
__global__ void k_smrebal(const float* __restrict__ logits, float* __restrict__ out) {
  __shared__ float red[4];
  const int tid = threadIdx.x;
  const long row = blockIdx.x;
  const float ub = 0.2f, lb = 0.0f;
  float4 lv = *(const float4*)(logits + row * 1024 + tid * 4);

  float m = fmaxf(fmaxf(lv.x, lv.y), fmaxf(lv.z, lv.w));
  m = blk_max(m, red, tid);
  float e[4] = {expf(lv.x - m), expf(lv.y - m), expf(lv.z - m), expf(lv.w - m)};
  float S = blk_sum(e[0] + e[1] + e[2] + e[3], red, tid);

  float old_[4], wc[4];
#pragma unroll
  for (int k = 0; k < 4; ++k) {
    float p = e[k] / S;
    old_[k] = p;
    wc[k] = fminf(fmaxf(p, lb), ub);
  }
  bool done = false;
  for (int it = 0; it < 32 && !done; ++it) {
    float d3 = 0.f, cnt = 0.f, nsum = 0.f;
#pragma unroll
    for (int k = 0; k < 4; ++k) {
      d3 += old_[k] - wc[k];
      bool mk = (wc[k] != ub);
      cnt += mk ? 1.f : 0.f;
      nsum += mk ? wc[k] : 0.f;
    }
    float leftover = blk_sum(d3, red, tid);
    float num = blk_sum(cnt, red, tid);
    float nom_sum = blk_sum(nsum, red, tid);
    float denom = (nom_sum == 0.f) ? 1.f : nom_sum;
    float wcn[4], mx = -1e30f;
#pragma unroll
    for (int k = 0; k < 4; ++k) {
      bool mk = (wc[k] != ub);
      wcn[k] = mk ? wc[k] + leftover * wc[k] / denom : wc[k];
      mx = fmaxf(mx, wcn[k]);
    }
    float gmx = blk_max(mx, red, tid);
    bool no_nom = (num == 0.f);
    bool over = (gmx > ub);
#pragma unroll
    for (int k = 0; k < 4; ++k) {
      float nxt = no_nom ? wc[k] : (over ? fminf(fmaxf(wcn[k], lb), ub) : wcn[k]);
      float oldn = no_nom ? old_[k] : wcn[k];
      wc[k] = nxt;
      old_[k] = oldn;
    }
    done = no_nom || !over;
  }
#pragma unroll
  for (int k = 0; k < 4; ++k) out[row * 1024 + tid * 4 + k] = wc[k];
}

// ---------------- host ----------------
extern "C" void kernel_launch(void* const* d_in, const int* in_sizes, int n_in,
                              void* d_out, int out_size, void* d_ws, size_t ws_size,
                              hipStream_t stream) {
  const float* x      = (const float*)d_in[0];
  const float* wih[2] = {(const float*)d_in[1], (const float*)d_in[5]};
  const float* whh[2] = {(const float*)d_in[2], (const float*)d_in[6]};
  const float* bih[2] = {(const float*)d_in[3], (const float*)d_in[7]};
  const float* bhh[2] = {(const float*)d_in[4], (const float*)d_in[8]};
  const float* fcw    = (const float*)d_in[9];
  const float* fcb    = (const float*)d_in[10];
  float* outp = (float*)d_out;

  unsigned char* ws = (unsigned char*)d_ws;
  size_t off = 0;
  auto alloc = [&](size_t bytes) -> void* {
    void* p = ws + off;
    off += (bytes + 255) & ~(size_t)255;
    return p;
  };
  bft* wihb0   = (bft*)alloc((size_t)G3 * DD * 2);
  bft* whhb0   = (bft*)alloc((size_t)G3 * HH * 2);
  bft* wihb1   = (bft*)alloc((size_t)G3 * HH * 2);
  bft* whhb1   = (bft*)alloc((size_t)G3 * HH * 2);
  bft* fcwb    = (bft*)alloc((size_t)1024 * 1024 * 2);
  bft* xp      = (bft*)alloc((size_t)BB * TC * G3 * 2);       // 100MB chunk x_proj
  bft* ring0   = (bft*)alloc((size_t)NRING * BB * DD * 2);    // 34.6MB L0 h ring
  bft* ring1   = (bft*)alloc((size_t)NRING * BB * DD * 2);    // 34.6MB L1 h ring
  float* hfc0  = (float*)alloc((size_t)BB * HH * 4);          // L0 chunk-boundary h
  float* hfc1  = (float*)alloc((size_t)BB * HH * 4);          // L1 chunk-boundary h
  int* flags   = (int*)alloc(1024);                           // 4 groups x 64 slots
  float* logits= (float*)alloc((size_t)BB * 1024 * 4);
  if (off > ws_size) return;  // insufficient workspace: leave output poisoned

  hipMemsetAsync(flags, 0, 1024, stream);

  // weight converts
  k_cvt<<<dim3(1536), dim3(256), 0, stream>>>(wih[0], wihb0, (long)G3 * DD);
  k_cvt<<<dim3(1536), dim3(256), 0, stream>>>(whh[0], whhb0, (long)G3 * HH);
  k_cvt<<<dim3(1536), dim3(256), 0, stream>>>(wih[1], wihb1, (long)G3 * HH);
  k_cvt<<<dim3(1536), dim3(256), 0, stream>>>(whh[1], whhb1, (long)G3 * HH);
  k_cvt<<<dim3(512),  dim3(256), 0, stream>>>(fcw, fcwb, (long)1024 * 1024);

  for (int c = 0; c < NCH; ++c) {
    int t0 = c * TC;
    int t0s = t0 % NRING;
    int first = (c == 0) ? 1 : 0;
    // L0 x-proj (fused x gather+convert): M = BB*TC = 16384, N = 3072, K = 1024
    k_gemm<1, 0><<<dim3(G3 / 128, (BB * TC) / 128), 256, 0, stream>>>(
        x, DD, wihb0, DD, bih[0], xp, G3, t0, DD);
    k_persist<<<dim3(256), dim3(256), 0, stream>>>(
        whhb0, bhh[0], xp, ring0, hfc0, flags, t0s, first, (2 * c) * TC);
    // L1 x-proj from ring0 (t-major slots)
    k_gemm<2, 0><<<dim3(G3 / 128, (BB * TC) / 128), 256, 0, stream>>>(
        ring0, DD, wihb1, DD, bih[1], xp, G3, t0s, DD);
    k_persist<<<dim3(256), dim3(256), 0, stream>>>(
        whhb1, bhh[1], xp, ring1, hfc1, flags, t0s, first, (2 * c + 1) * TC);
  }
  // FC + SiLU on final h: t=127 -> ring1 slot 127%33 = 28
  const bft* hfin = ring1 + (size_t)((TT - 1) % NRING) * BB * DD;
  k_gemm<0, 1><<<dim3(1024 / 128, BB / 128), 256, 0, stream>>>(
      hfin, DD, fcwb, HH, fcb, logits, 1024, 0, HH);
  k_smrebal<<<dim3(BB), 256, 0, stream>>>(logits, outp);
}